// Round 3
// baseline (104.531 us; speedup 1.0000x reference)
//
#include <hip/hip_runtime.h>

// Problem constants
#define Bz 4
#define Nn 1024
#define Cc 23
#define Hh 100
#define H4 25           // Hh/4
#define BT 128          // b-tile staged in LDS
#define BSPLIT 4        // b-range split across blocks
#define BCHUNK 256      // Nn / BSPLIT

// ws layout (float offsets)
#define FW_OFF    0                    // [4][25][1024] float4 = 409600 floats
#define COEF_OFF  409600               // [100] float4 = 400 floats
#define BIAS_OFF  410000               // [4]
#define CONV4_OFF 410004               // [BSPLIT][4][1024] partial sums = 16384

// ---------------------------------------------------------------------------
// prep: fw[z][h4][b] = float4 over h=4*h4+j of sum_c W2[h][c]*f[z][b][c]
//       bias[z] = sum_b sum_c b2[c]*f[z][b][c]
//       coef[h] = {W1[0][h], W1[1][h], W1[2][h], b1[h]}
// ---------------------------------------------------------------------------
__global__ void prep_kernel(const float* __restrict__ f,
                            const float* __restrict__ W1,
                            const float* __restrict__ b1,
                            const float* __restrict__ W2,
                            const float* __restrict__ b2,
                            float* __restrict__ ws) {
    int blk = blockIdx.x;
    int t = threadIdx.x;
    if (blk < 400) {
        int idx = blk * 256 + t;          // 0..102399 = 4*25*1024
        int z = idx / 25600;
        int rem = idx - z * 25600;
        int h4 = rem >> 10;
        int b = rem & 1023;
        const float* frow = f + (z * Nn + b) * Cc;
        float fr[Cc];
        #pragma unroll
        for (int c = 0; c < Cc; ++c) fr[c] = frow[c];
        float o[4];
        #pragma unroll
        for (int j = 0; j < 4; ++j) {
            const float* wrow = W2 + (h4 * 4 + j) * Cc;
            float s = 0.f;
            #pragma unroll
            for (int c = 0; c < Cc; ++c) s = fmaf(fr[c], wrow[c], s);
            o[j] = s;
        }
        reinterpret_cast<float4*>(ws + FW_OFF)[(z * H4 + h4) * Nn + b] =
            make_float4(o[0], o[1], o[2], o[3]);
    } else if (blk < 404) {
        int z = blk - 400;
        float s = 0.f;
        for (int b = t; b < Nn; b += 256) {
            const float* frow = f + (z * Nn + b) * Cc;
            #pragma unroll
            for (int c = 0; c < Cc; ++c) s = fmaf(frow[c], b2[c], s);
        }
        __shared__ float red[256];
        red[t] = s; __syncthreads();
        for (int off = 128; off; off >>= 1) {
            if (t < off) red[t] += red[t + off];
            __syncthreads();
        }
        if (t == 0) ws[BIAS_OFF + z] = red[0];
    } else {
        if (t < Hh) {
            reinterpret_cast<float4*>(ws + COEF_OFF)[t] =
                make_float4(W1[t], W1[Hh + t], W1[2 * Hh + t], b1[t]);
        }
    }
}

// ---------------------------------------------------------------------------
// main conv. Each wave owns 4 a's (wave-uniform), lanes = b. Each block:
// 8 waves = 32 a's, one z, one quarter of the b-range (BCHUNK=256).
// Grid = 4*z  x 32 a-groups x 4 b-splits = 512 blocks.
// One fv ds_read_b128 serves 4 edges; coef comes from global (uniform index
// -> s_load scalar pipe). Partial sums written to CONV4 (no atomics).
// ---------------------------------------------------------------------------
__global__ __launch_bounds__(512, 2)
void conv_kernel(const float* __restrict__ geom,
                 const float4* __restrict__ fw,     // [4][25][1024]
                 const float4* __restrict__ coef,   // [100] = {W1r0,W1r1,W1r2,b1} per h
                 float* __restrict__ conv4) {       // [BSPLIT][4][1024]
    __shared__ float4 fw_s[H4 * BT];   // 51200 B
    int bid = blockIdx.x;
    int z = bid >> 7;
    int rem = bid & 127;
    int ag = rem >> 2;          // a-group 0..31
    int bs = rem & 3;           // b-split 0..3
    int t = threadIdx.x;
    int wave = t >> 6, lane = t & 63;
    int a0 = ag * 32 + wave * 4;

    float gax[4], gay[4], gaz[4];
    #pragma unroll
    for (int i = 0; i < 4; ++i) {
        const float* g = geom + (z * Nn + a0 + i) * 3;
        gax[i] = g[0]; gay[i] = g[1]; gaz[i] = g[2];
    }
    const float4* fwz = fw + z * (H4 * Nn);
    float acc[4] = {0.f, 0.f, 0.f, 0.f};
    int bbase = bs * BCHUNK;

    for (int tile = 0; tile < BCHUNK / BT; ++tile) {   // 2 tiles
        int b0 = bbase + tile * BT;
        __syncthreads();
        for (int j = t; j < H4 * BT; j += 512)
            fw_s[j] = fwz[(j >> 7) * Nn + b0 + (j & (BT - 1))];
        __syncthreads();
        #pragma unroll
        for (int bsub = 0; bsub < BT; bsub += 64) {
            int bl = bsub + lane;
            const float* gb = geom + (z * Nn + b0 + bl) * 3;
            float gbx = gb[0], gby = gb[1], gbz = gb[2];
            float s0[4], s1[4], s2[4];
            #pragma unroll
            for (int i = 0; i < 4; ++i) {
                float dx = gax[i] - gbx, dy = gay[i] - gby, dz = gaz[i] - gbz;
                float r = sqrtf(fmaf(dx, dx, fmaf(dy, dy, fmaf(dz, dz, 1e-12f))));
                float u = r * (2.0f / 3.0f);
                float cp = __builtin_amdgcn_cosf(0.5f * u);   // cos(pi*u)
                float p = fmaf(0.5f, cp, 0.5f);
                float m = fmaf(-0.5f, cp, 0.5f);
                s0[i] = (u < 1.0f) ? p : 0.0f;
                s1[i] = (u < 2.0f) ? m : 0.0f;
                s2[i] = (u > 1.0f && u < 3.0f) ? p : 0.0f;
            }
            #pragma unroll 5
            for (int h4 = 0; h4 < H4; ++h4) {
                float4 fv = fw_s[h4 * BT + bl];
                float4 c0 = coef[h4 * 4 + 0];
                float4 c1 = coef[h4 * 4 + 1];
                float4 c2 = coef[h4 * 4 + 2];
                float4 c3 = coef[h4 * 4 + 3];
                #pragma unroll
                for (int i = 0; i < 4; ++i) {
                    float h0 = fmaf(s0[i], c0.x, fmaf(s1[i], c0.y, fmaf(s2[i], c0.z, c0.w)));
                    float h1 = fmaf(s0[i], c1.x, fmaf(s1[i], c1.y, fmaf(s2[i], c1.z, c1.w)));
                    float h2 = fmaf(s0[i], c2.x, fmaf(s1[i], c2.y, fmaf(s2[i], c2.z, c2.w)));
                    float h3 = fmaf(s0[i], c3.x, fmaf(s1[i], c3.y, fmaf(s2[i], c3.z, c3.w)));
                    acc[i] = fmaf(fmaxf(h0, 0.f), fv.x, acc[i]);
                    acc[i] = fmaf(fmaxf(h1, 0.f), fv.y, acc[i]);
                    acc[i] = fmaf(fmaxf(h2, 0.f), fv.z, acc[i]);
                    acc[i] = fmaf(fmaxf(h3, 0.f), fv.w, acc[i]);
                }
            }
        }
    }
    #pragma unroll
    for (int off = 32; off; off >>= 1) {
        #pragma unroll
        for (int i = 0; i < 4; ++i) acc[i] += __shfl_down(acc[i], off);
    }
    if (lane == 0) {
        #pragma unroll
        for (int i = 0; i < 4; ++i)
            conv4[((bs * 4 + z) << 10) + a0 + i] = acc[i];
    }
}

// ---------------------------------------------------------------------------
// head: sum 4 b-split partials, add bias, scale 1/32, then fc1->fc2->fc3
// ---------------------------------------------------------------------------
__global__ void head_kernel(const float* __restrict__ ws,
                            const float* __restrict__ Wf1, const float* __restrict__ bf1,
                            const float* __restrict__ Wf2, const float* __restrict__ bf2,
                            const float* __restrict__ Wf3, const float* __restrict__ bf3,
                            float* __restrict__ out) {
    __shared__ float x1[Bz][30];
    __shared__ float x2[Bz][10];
    int t = threadIdx.x;
    if (t < 120) {
        int z = t / 30, d = t % 30;
        const float* c4 = ws + CONV4_OFF;
        float biasz = ws[BIAS_OFF + z];
        float a0 = 0, a1 = 0, a2 = 0, a3 = 0;
        for (int k = 0; k < Nn; k += 4) {
            #pragma unroll
            for (int j = 0; j < 4; ++j) {
                int kk = k + j;
                float raw = c4[(0 * 4 + z) * Nn + kk] + c4[(1 * 4 + z) * Nn + kk]
                          + c4[(2 * 4 + z) * Nn + kk] + c4[(3 * 4 + z) * Nn + kk];
                float x = (raw + biasz) * 0.03125f;
                if (j == 0) a0 = fmaf(x, Wf1[kk * 30 + d], a0);
                else if (j == 1) a1 = fmaf(x, Wf1[kk * 30 + d], a1);
                else if (j == 2) a2 = fmaf(x, Wf1[kk * 30 + d], a2);
                else a3 = fmaf(x, Wf1[kk * 30 + d], a3);
            }
        }
        x1[z][d] = fmaxf((a0 + a1) + (a2 + a3) + bf1[d], 0.f);
    }
    __syncthreads();
    if (t < 40) {
        int z = t / 10, d = t % 10;
        float s = bf2[d];
        #pragma unroll
        for (int k = 0; k < 30; ++k) s = fmaf(x1[z][k], Wf2[k * 10 + d], s);
        x2[z][d] = fmaxf(s, 0.f);
    }
    __syncthreads();
    if (t < Bz) {
        float s = bf3[0];
        #pragma unroll
        for (int k = 0; k < 10; ++k) s = fmaf(x2[t][k], Wf3[k], s);
        out[t] = s;
    }
}

extern "C" void kernel_launch(void* const* d_in, const int* in_sizes, int n_in,
                              void* d_out, int out_size, void* d_ws, size_t ws_size,
                              hipStream_t stream) {
    const float* f   = (const float*)d_in[0];
    const float* geo = (const float*)d_in[1];
    const float* W1  = (const float*)d_in[2];
    const float* b1  = (const float*)d_in[3];
    const float* W2  = (const float*)d_in[4];
    const float* b2  = (const float*)d_in[5];
    const float* Wf1 = (const float*)d_in[6];
    const float* bf1 = (const float*)d_in[7];
    const float* Wf2 = (const float*)d_in[8];
    const float* bf2 = (const float*)d_in[9];
    const float* Wf3 = (const float*)d_in[10];
    const float* bf3 = (const float*)d_in[11];
    float* ws  = (float*)d_ws;
    float* out = (float*)d_out;

    hipLaunchKernelGGL(prep_kernel, dim3(405), dim3(256), 0, stream, f, W1, b1, W2, b2, ws);
    hipLaunchKernelGGL(conv_kernel, dim3(512), dim3(512), 0, stream,
                       geo,
                       reinterpret_cast<const float4*>(ws + FW_OFF),
                       reinterpret_cast<const float4*>(ws + COEF_OFF),
                       ws + CONV4_OFF);
    hipLaunchKernelGGL(head_kernel, dim3(1), dim3(128), 0, stream,
                       ws, Wf1, bf1, Wf2, bf2, Wf3, bf3, out);
}

// Round 4
// 62.252 us; speedup vs baseline: 1.6792x; 1.6792x over previous
//
#include <hip/hip_runtime.h>

typedef float v2f __attribute__((ext_vector_type(2)));

// Problem constants
#define Bz 4
#define Nn 1024
#define Cc 23
#define Hh 100
#define H4 25           // Hh/4
#define BT 128          // b-tile staged in LDS
#define BSPLIT 4        // b-range split across blocks
#define BCHUNK 256      // Nn / BSPLIT

// ws layout (float offsets)
#define FW_OFF    0                    // [4][25][1024] float4 = 409600 floats
#define BIAS_OFF  409600               // [4]
#define CONV4_OFF 409604               // [BSPLIT][4][1024] = 16384 floats
#define X1_OFF    425988               // [4][30] = 120 floats

// radial-MLP coefficients, repacked: coef_c[h4*4+r] = over j=0..3 of
//   r<3 : W1[r][4*h4+j]   r==3 : b1[4*h4+j]
// Lives in constant addrspace -> uniform-index reads become s_load (scalar pipe).
__constant__ float4 coef_c[Hh];

// ---------------------------------------------------------------------------
// prep: fw[z][h4][b] (float4 over h) = sum_c W2[h][c]*f[z][b][c]
//       bias[z] = sum_b sum_c b2[c]*f[z][b][c];  coef_c repack
// ---------------------------------------------------------------------------
__global__ void prep_kernel(const float* __restrict__ f,
                            const float* __restrict__ W1,
                            const float* __restrict__ b1,
                            const float* __restrict__ W2,
                            const float* __restrict__ b2,
                            float* __restrict__ ws,
                            float4* __restrict__ coef_out) {
    int blk = blockIdx.x;
    int t = threadIdx.x;
    if (blk < 400) {
        int idx = blk * 256 + t;          // 0..102399 = 4*25*1024
        int z = idx / 25600;
        int rem = idx - z * 25600;
        int h4 = rem >> 10;
        int b = rem & 1023;
        const float* frow = f + (z * Nn + b) * Cc;
        float fr[Cc];
        #pragma unroll
        for (int c = 0; c < Cc; ++c) fr[c] = frow[c];
        float o[4];
        #pragma unroll
        for (int j = 0; j < 4; ++j) {
            const float* wrow = W2 + (h4 * 4 + j) * Cc;
            float s = 0.f;
            #pragma unroll
            for (int c = 0; c < Cc; ++c) s = fmaf(fr[c], wrow[c], s);
            o[j] = s;
        }
        reinterpret_cast<float4*>(ws + FW_OFF)[(z * H4 + h4) * Nn + b] =
            make_float4(o[0], o[1], o[2], o[3]);
    } else if (blk < 404) {
        int z = blk - 400;
        float s = 0.f;
        for (int b = t; b < Nn; b += 256) {
            const float* frow = f + (z * Nn + b) * Cc;
            #pragma unroll
            for (int c = 0; c < Cc; ++c) s = fmaf(frow[c], b2[c], s);
        }
        __shared__ float red[256];
        red[t] = s; __syncthreads();
        for (int off = 128; off; off >>= 1) {
            if (t < off) red[t] += red[t + off];
            __syncthreads();
        }
        if (t == 0) ws[BIAS_OFF + z] = red[0];
    } else {
        if (t < Hh) {
            int h4 = t >> 2, r = t & 3;
            int h0 = 4 * h4;
            float4 v;
            if (r < 3) v = make_float4(W1[r * Hh + h0], W1[r * Hh + h0 + 1],
                                       W1[r * Hh + h0 + 2], W1[r * Hh + h0 + 3]);
            else       v = make_float4(b1[h0], b1[h0 + 1], b1[h0 + 2], b1[h0 + 3]);
            coef_out[t] = v;
        }
    }
}

// ---------------------------------------------------------------------------
// main conv. Wave owns 4 a's (uniform), lanes = b. Block: 8 waves = 32 a's,
// one z, one quarter of b (BCHUNK=256). Grid = 512 blocks.
// coef from __constant__ (s_load); fv from LDS (b128); packed-fp32 math.
// ---------------------------------------------------------------------------
__global__ __launch_bounds__(512, 2)
void conv_kernel(const float* __restrict__ geom,
                 const float4* __restrict__ fw,     // [4][25][1024]
                 float* __restrict__ conv4) {       // [BSPLIT][4][1024]
    __shared__ float4 fw_s[H4 * BT];   // 51200 B
    int bid = blockIdx.x;
    int z = bid >> 7;
    int rem = bid & 127;
    int ag = rem >> 2;          // a-group 0..31
    int bs = rem & 3;           // b-split 0..3
    int t = threadIdx.x;
    int wave = t >> 6, lane = t & 63;
    int a0 = ag * 32 + wave * 4;

    float gax[4], gay[4], gaz[4];
    #pragma unroll
    for (int i = 0; i < 4; ++i) {
        const float* g = geom + (z * Nn + a0 + i) * 3;
        gax[i] = g[0]; gay[i] = g[1]; gaz[i] = g[2];
    }
    int bbase = bs * BCHUNK;
    float gbx[4], gby[4], gbz[4];     // this lane's 4 b geometries, hoisted
    #pragma unroll
    for (int k = 0; k < 4; ++k) {
        const float* g = geom + (z * Nn + bbase + k * 64 + lane) * 3;
        gbx[k] = g[0]; gby[k] = g[1]; gbz[k] = g[2];
    }
    const float4* fwz = fw + z * (H4 * Nn);
    v2f acc[4] = {(v2f){0.f,0.f},(v2f){0.f,0.f},(v2f){0.f,0.f},(v2f){0.f,0.f}};

    for (int tile = 0; tile < 2; ++tile) {
        int b0 = bbase + tile * BT;
        __syncthreads();
        for (int j = t; j < H4 * BT; j += 512)
            fw_s[j] = fwz[(j >> 7) * Nn + b0 + (j & (BT - 1))];
        __syncthreads();
        #pragma unroll
        for (int bsub = 0; bsub < 2; ++bsub) {
            int k = tile * 2 + bsub;
            v2f s0v[4], s1v[4], s2v[4];
            #pragma unroll
            for (int i = 0; i < 4; ++i) {
                float dx = gax[i] - gbx[k], dy = gay[i] - gby[k], dz = gaz[i] - gbz[k];
                float r = sqrtf(fmaf(dx, dx, fmaf(dy, dy, fmaf(dz, dz, 1e-12f))));
                float u = r * (2.0f / 3.0f);
                float cp = __builtin_amdgcn_cosf(0.5f * u);   // cos(pi*u)
                float p = fmaf(0.5f, cp, 0.5f);
                float m = fmaf(-0.5f, cp, 0.5f);
                float s0 = (u < 1.0f) ? p : 0.0f;
                float s1 = (u < 2.0f) ? m : 0.0f;
                float s2 = (u > 1.0f && u < 3.0f) ? p : 0.0f;
                s0v[i] = (v2f){s0, s0};
                s1v[i] = (v2f){s1, s1};
                s2v[i] = (v2f){s2, s2};
            }
            const float4* fwp = fw_s + bsub * 64 + lane;
            #pragma unroll 5
            for (int h4 = 0; h4 < H4; ++h4) {
                float4 fv = fwp[h4 * BT];
                float4 c0 = coef_c[h4 * 4 + 0];
                float4 c1 = coef_c[h4 * 4 + 1];
                float4 c2 = coef_c[h4 * 4 + 2];
                float4 c3 = coef_c[h4 * 4 + 3];
                v2f c0lo = (v2f){c0.x, c0.y}, c0hi = (v2f){c0.z, c0.w};
                v2f c1lo = (v2f){c1.x, c1.y}, c1hi = (v2f){c1.z, c1.w};
                v2f c2lo = (v2f){c2.x, c2.y}, c2hi = (v2f){c2.z, c2.w};
                v2f c3lo = (v2f){c3.x, c3.y}, c3hi = (v2f){c3.z, c3.w};
                v2f fvlo = (v2f){fv.x, fv.y}, fvhi = (v2f){fv.z, fv.w};
                #pragma unroll
                for (int i = 0; i < 4; ++i) {
                    v2f h0 = __builtin_elementwise_fma(s0v[i], c0lo,
                              __builtin_elementwise_fma(s1v[i], c1lo,
                               __builtin_elementwise_fma(s2v[i], c2lo, c3lo)));
                    v2f h1 = __builtin_elementwise_fma(s0v[i], c0hi,
                              __builtin_elementwise_fma(s1v[i], c1hi,
                               __builtin_elementwise_fma(s2v[i], c2hi, c3hi)));
                    h0 = __builtin_elementwise_max(h0, (v2f){0.f, 0.f});
                    h1 = __builtin_elementwise_max(h1, (v2f){0.f, 0.f});
                    acc[i] = __builtin_elementwise_fma(h0, fvlo, acc[i]);
                    acc[i] = __builtin_elementwise_fma(h1, fvhi, acc[i]);
                }
            }
        }
    }
    #pragma unroll
    for (int i = 0; i < 4; ++i) {
        float a = acc[i].x + acc[i].y;
        #pragma unroll
        for (int off = 32; off; off >>= 1) a += __shfl_down(a, off);
        if (lane == 0) conv4[((bs * 4 + z) << 10) + a0 + i] = a;
    }
}

// ---------------------------------------------------------------------------
// reduce_fc1: one block per (z,d). Sum 4 partials + bias, /32, dot Wf1 col d.
// ---------------------------------------------------------------------------
__global__ void reduce_fc1_kernel(const float* __restrict__ ws,
                                  const float* __restrict__ Wf1,
                                  const float* __restrict__ bf1,
                                  float* __restrict__ x1out) {
    int z = blockIdx.x / 30, d = blockIdx.x % 30;
    int t = threadIdx.x;                      // 256
    const float* c4 = ws + CONV4_OFF;
    float biasz = ws[BIAS_OFF + z] * 0.03125f;
    float acc = 0.f;
    for (int k = t; k < Nn; k += 256) {
        float raw = c4[(0 * 4 + z) * Nn + k] + c4[(1 * 4 + z) * Nn + k]
                  + c4[(2 * 4 + z) * Nn + k] + c4[(3 * 4 + z) * Nn + k];
        float x = fmaf(raw, 0.03125f, biasz);
        acc = fmaf(x, Wf1[k * 30 + d], acc);
    }
    #pragma unroll
    for (int off = 32; off; off >>= 1) acc += __shfl_down(acc, off);
    __shared__ float red[4];
    if ((t & 63) == 0) red[t >> 6] = acc;
    __syncthreads();
    if (t == 0) {
        float s = red[0] + red[1] + red[2] + red[3];
        x1out[z * 30 + d] = fmaxf(s + bf1[d], 0.f);
    }
}

// ---------------------------------------------------------------------------
// fc23: [4,30] -> relu fc2(10) -> fc3(1)
// ---------------------------------------------------------------------------
__global__ void fc23_kernel(const float* __restrict__ ws,
                            const float* __restrict__ Wf2, const float* __restrict__ bf2,
                            const float* __restrict__ Wf3, const float* __restrict__ bf3,
                            float* __restrict__ out) {
    __shared__ float x2[Bz][10];
    int t = threadIdx.x;
    const float* x1 = ws + X1_OFF;
    if (t < 40) {
        int z = t / 10, d = t % 10;
        float s = bf2[d];
        #pragma unroll
        for (int kk = 0; kk < 30; ++kk) s = fmaf(x1[z * 30 + kk], Wf2[kk * 10 + d], s);
        x2[z][d] = fmaxf(s, 0.f);
    }
    __syncthreads();
    if (t < Bz) {
        float s = bf3[0];
        #pragma unroll
        for (int kk = 0; kk < 10; ++kk) s = fmaf(x2[t][kk], Wf3[kk], s);
        out[t] = s;
    }
}

extern "C" void kernel_launch(void* const* d_in, const int* in_sizes, int n_in,
                              void* d_out, int out_size, void* d_ws, size_t ws_size,
                              hipStream_t stream) {
    const float* f   = (const float*)d_in[0];
    const float* geo = (const float*)d_in[1];
    const float* W1  = (const float*)d_in[2];
    const float* b1  = (const float*)d_in[3];
    const float* W2  = (const float*)d_in[4];
    const float* b2  = (const float*)d_in[5];
    const float* Wf1 = (const float*)d_in[6];
    const float* bf1 = (const float*)d_in[7];
    const float* Wf2 = (const float*)d_in[8];
    const float* bf2 = (const float*)d_in[9];
    const float* Wf3 = (const float*)d_in[10];
    const float* bf3 = (const float*)d_in[11];
    float* ws  = (float*)d_ws;
    float* out = (float*)d_out;

    // __constant__ symbol address (host-side query, graph-capture safe)
    float4* coef_dev = nullptr;
    hipGetSymbolAddress((void**)&coef_dev, HIP_SYMBOL(coef_c));

    hipLaunchKernelGGL(prep_kernel, dim3(405), dim3(256), 0, stream,
                       f, W1, b1, W2, b2, ws, coef_dev);
    hipLaunchKernelGGL(conv_kernel, dim3(512), dim3(512), 0, stream,
                       geo, reinterpret_cast<const float4*>(ws + FW_OFF), ws + CONV4_OFF);
    hipLaunchKernelGGL(reduce_fc1_kernel, dim3(120), dim3(256), 0, stream,
                       ws, Wf1, bf1, ws + X1_OFF);
    hipLaunchKernelGGL(fc23_kernel, dim3(1), dim3(64), 0, stream,
                       ws, Wf2, bf2, Wf3, bf3, out);
}

// Round 5
// 35.839 us; speedup vs baseline: 2.9167x; 1.7370x over previous
//
#include <hip/hip_runtime.h>

#define Bz 4
#define Nn 1024
#define Cc 23
#define Hh 100
#define KNOTS 257            // v = r/1.5 tabulated on [0,3], 256 cells
#define DSTRIDE 264          // floats per D row (257 padded)
#define USTRIDE 24           // U row floats
#define BSPL 32              // b-splits across conv blocks
#define GRP 16               // D rows staged per LDS group

// ws float offsets
#define D_OFF     0                 // [4][1024][264] = 1081344
#define U_OFF     1081344           // [257][24] = 6168
#define G4_OFF    1087512           // [4096][4] = 16384 (16B aligned)
#define BIAS_OFF  1103896           // [4]
#define P_OFF     1103900           // [32][4][1024] = 131072
#define X1_OFF    1234972           // [120]

// ---------------------------------------------------------------------------
// prep: geom4 padding, radial table U[k][c] = sum_h relu(g_h(v_k))*W2[h][c],
//       bias[z] = sum_b sum_c b2[c]*f[z][b][c]
// grid: 16 geom4 blocks + 5 knot blocks + 4 bias blocks = 25
// ---------------------------------------------------------------------------
__global__ void prep_kernel(const float* __restrict__ f,
                            const float* __restrict__ geom,
                            const float* __restrict__ W1,
                            const float* __restrict__ b1,
                            const float* __restrict__ W2,
                            const float* __restrict__ b2,
                            float* __restrict__ ws) {
    int blk = blockIdx.x;
    int t = threadIdx.x;
    if (blk < 16) {                       // geom4[zb] = (x,y,z,0)
        int zb = blk * 256 + t;
        const float* g = geom + zb * 3;
        reinterpret_cast<float4*>(ws + G4_OFF)[zb] =
            make_float4(g[0], g[1], g[2], 0.f);
    } else if (blk < 21) {                // radial table knots
        __shared__ float up[4][64][24];
        int kl = t & 63, hq = t >> 6;
        int kn = (blk - 16) * 64 + kl;
        float v = (float)kn * (3.0f / 256.0f);
        const float HPI = 1.57079632679f;
        float c0 = cosf(HPI * v);
        float c1 = cosf(HPI * (v - 1.0f));
        float c2 = cosf(HPI * (v - 2.0f));
        float s0 = (fabsf(v) < 1.0f) ? c0 * c0 : 0.0f;
        float s1 = (fabsf(v - 1.0f) < 1.0f) ? c1 * c1 : 0.0f;
        float s2 = (fabsf(v - 2.0f) < 1.0f) ? c2 * c2 : 0.0f;
        float uacc[Cc];
        #pragma unroll
        for (int c = 0; c < Cc; ++c) uacc[c] = 0.f;
        for (int h = hq * 25; h < hq * 25 + 25; ++h) {
            float hh = fmaxf(fmaf(s0, W1[h],
                              fmaf(s1, W1[Hh + h],
                               fmaf(s2, W1[2 * Hh + h], b1[h]))), 0.f);
            #pragma unroll
            for (int c = 0; c < Cc; ++c)
                uacc[c] = fmaf(hh, W2[h * Cc + c], uacc[c]);
        }
        #pragma unroll
        for (int c = 0; c < Cc; ++c) up[hq][kl][c] = uacc[c];
        __syncthreads();
        if (hq == 0 && kn < KNOTS) {
            #pragma unroll
            for (int c = 0; c < Cc; ++c)
                ws[U_OFF + kn * USTRIDE + c] =
                    (up[0][kl][c] + up[1][kl][c]) + (up[2][kl][c] + up[3][kl][c]);
        }
    } else {                              // bias[z]
        int z = blk - 21;
        float s = 0.f;
        for (int b = t; b < Nn; b += 256) {
            const float* frow = f + (z * Nn + b) * Cc;
            #pragma unroll
            for (int c = 0; c < Cc; ++c) s = fmaf(frow[c], b2[c], s);
        }
        __shared__ float red[256];
        red[t] = s; __syncthreads();
        for (int off = 128; off; off >>= 1) {
            if (t < off) red[t] += red[t + off];
            __syncthreads();
        }
        if (t == 0) ws[BIAS_OFF + z] = red[0];
    }
}

// ---------------------------------------------------------------------------
// dgemm: D[zb][k] = sum_c U[k][c] * f[zb][c]   (K=23)
// grid 640 x 64: kg = blk%5 (k = kg*64+lane), zb chunk = blk/5 (32 rows).
// U held in 23 VGPRs per lane; f row via wave-uniform scalar loads.
// ---------------------------------------------------------------------------
__global__ __launch_bounds__(64)
void dgemm_kernel(const float* __restrict__ f,
                  const float* __restrict__ u_g,     // ws + U_OFF
                  float* __restrict__ D) {           // ws + D_OFF
    int lane = threadIdx.x;
    int kg = blockIdx.x % 5;
    int zbc = blockIdx.x / 5;           // 0..127, 32 zb each
    int k = kg * 64 + lane;
    bool act = k < KNOTS;
    int kc = act ? k : 0;
    float ur[Cc];
    #pragma unroll
    for (int c = 0; c < Cc; ++c) ur[c] = u_g[kc * USTRIDE + c];
    int zb0 = zbc * 32;
    #pragma unroll 4
    for (int i = 0; i < 32; ++i) {
        int zb = zb0 + i;
        const float* frow = f + zb * Cc;
        float a0 = 0.f, a1 = 0.f, a2 = 0.f, a3 = 0.f;
        #pragma unroll
        for (int c = 0; c < 20; c += 4) {
            a0 = fmaf(frow[c + 0], ur[c + 0], a0);
            a1 = fmaf(frow[c + 1], ur[c + 1], a1);
            a2 = fmaf(frow[c + 2], ur[c + 2], a2);
            a3 = fmaf(frow[c + 3], ur[c + 3], a3);
        }
        a0 = fmaf(frow[20], ur[20], a0);
        a1 = fmaf(frow[21], ur[21], a1);
        a2 = fmaf(frow[22], ur[22], a2);
        if (act) D[zb * DSTRIDE + k] = (a0 + a1) + (a2 + a3);
    }
}

// ---------------------------------------------------------------------------
// conv: per edge (a,b): r -> mu -> lerp(D[z][b][:]) ; acc over block's 32 b's.
// Block 256 threads <-> 256 a's; grid = z(4) x aq(4) x s(32) = 512 blocks.
// D rows staged in LDS 16 at a time; gb geometry via uniform scalar loads.
// ---------------------------------------------------------------------------
__global__ __launch_bounds__(256, 2)
void conv_kernel(const float4* __restrict__ geom4,   // ws + G4_OFF
                 const float* __restrict__ D,        // ws + D_OFF
                 float* __restrict__ P) {            // ws + P_OFF
    __shared__ float lds[GRP * DSTRIDE];   // 16896 B
    int bid = blockIdx.x;
    int s = bid & 31;
    int aq = (bid >> 5) & 3;
    int z = bid >> 7;
    int t = threadIdx.x;
    int a = aq * 256 + t;

    float4 ga = geom4[z * Nn + a];
    float acc = 0.f;
    int b0 = s * 32;

    for (int g = 0; g < 2; ++g) {
        int bg = b0 + g * GRP;
        __syncthreads();
        const float4* src = reinterpret_cast<const float4*>(D + (z * Nn + bg) * DSTRIDE);
        for (int j = t; j < GRP * DSTRIDE / 4; j += 256)
            reinterpret_cast<float4*>(lds)[j] = src[j];
        __syncthreads();
        float4 gbs[GRP];
        #pragma unroll
        for (int i = 0; i < GRP; ++i) gbs[i] = geom4[z * Nn + bg + i];
        #pragma unroll
        for (int bl = 0; bl < GRP; ++bl) {
            float dx = ga.x - gbs[bl].x;
            float dy = ga.y - gbs[bl].y;
            float dz = ga.z - gbs[bl].z;
            float r = sqrtf(fmaf(dx, dx, fmaf(dy, dy, fmaf(dz, dz, 1e-12f))));
            float mu = fminf(r * 56.8888889f, 255.999f);   // v*256/3, clamped
            int m = (int)mu;
            float tt = mu - (float)m;
            const float* row = lds + bl * DSTRIDE + m;
            float d0 = row[0];
            float d1 = row[1];
            acc += fmaf(tt, d1 - d0, d0);
        }
    }
    P[((s * Bz + z) << 10) + a] = acc;
}

// ---------------------------------------------------------------------------
// reduce_fc1: x1[z][d] = relu( sum_k ((sum_s P[s][z][k]) + bias)/32 * Wf1[k][d] + bf1[d] )
// ---------------------------------------------------------------------------
__global__ void reduce_fc1_kernel(const float* __restrict__ ws,
                                  const float* __restrict__ Wf1,
                                  const float* __restrict__ bf1,
                                  float* __restrict__ x1out) {
    int z = blockIdx.x / 30, d = blockIdx.x % 30;
    int t = threadIdx.x;                      // 256
    const float* Pp = ws + P_OFF;
    float biasz = ws[BIAS_OFF + z];
    float acc = 0.f;
    for (int k = t; k < Nn; k += 256) {
        float raw = 0.f;
        #pragma unroll
        for (int sp = 0; sp < BSPL; ++sp)
            raw += Pp[((sp * Bz + z) << 10) + k];
        float x = (raw + biasz) * 0.03125f;
        acc = fmaf(x, Wf1[k * 30 + d], acc);
    }
    #pragma unroll
    for (int off = 32; off; off >>= 1) acc += __shfl_down(acc, off);
    __shared__ float red[4];
    if ((t & 63) == 0) red[t >> 6] = acc;
    __syncthreads();
    if (t == 0) {
        float sm = (red[0] + red[1]) + (red[2] + red[3]);
        x1out[z * 30 + d] = fmaxf(sm + bf1[d], 0.f);
    }
}

// ---------------------------------------------------------------------------
// fc23: [4,30] -> relu fc2(10) -> fc3(1)
// ---------------------------------------------------------------------------
__global__ void fc23_kernel(const float* __restrict__ ws,
                            const float* __restrict__ Wf2, const float* __restrict__ bf2,
                            const float* __restrict__ Wf3, const float* __restrict__ bf3,
                            float* __restrict__ out) {
    __shared__ float x2[Bz][10];
    int t = threadIdx.x;
    const float* x1 = ws + X1_OFF;
    if (t < 40) {
        int z = t / 10, d = t % 10;
        float sm = bf2[d];
        #pragma unroll
        for (int kk = 0; kk < 30; ++kk) sm = fmaf(x1[z * 30 + kk], Wf2[kk * 10 + d], sm);
        x2[z][d] = fmaxf(sm, 0.f);
    }
    __syncthreads();
    if (t < Bz) {
        float sm = bf3[0];
        #pragma unroll
        for (int kk = 0; kk < 10; ++kk) sm = fmaf(x2[t][kk], Wf3[kk], sm);
        out[t] = sm;
    }
}

extern "C" void kernel_launch(void* const* d_in, const int* in_sizes, int n_in,
                              void* d_out, int out_size, void* d_ws, size_t ws_size,
                              hipStream_t stream) {
    const float* f   = (const float*)d_in[0];
    const float* geo = (const float*)d_in[1];
    const float* W1  = (const float*)d_in[2];
    const float* b1  = (const float*)d_in[3];
    const float* W2  = (const float*)d_in[4];
    const float* b2  = (const float*)d_in[5];
    const float* Wf1 = (const float*)d_in[6];
    const float* bf1 = (const float*)d_in[7];
    const float* Wf2 = (const float*)d_in[8];
    const float* bf2 = (const float*)d_in[9];
    const float* Wf3 = (const float*)d_in[10];
    const float* bf3 = (const float*)d_in[11];
    float* ws  = (float*)d_ws;
    float* out = (float*)d_out;

    hipLaunchKernelGGL(prep_kernel, dim3(25), dim3(256), 0, stream,
                       f, geo, W1, b1, W2, b2, ws);
    hipLaunchKernelGGL(dgemm_kernel, dim3(640), dim3(64), 0, stream,
                       f, ws + U_OFF, ws + D_OFF);
    hipLaunchKernelGGL(conv_kernel, dim3(512), dim3(256), 0, stream,
                       reinterpret_cast<const float4*>(ws + G4_OFF),
                       ws + D_OFF, ws + P_OFF);
    hipLaunchKernelGGL(reduce_fc1_kernel, dim3(120), dim3(256), 0, stream,
                       ws, Wf1, bf1, ws + X1_OFF);
    hipLaunchKernelGGL(fc23_kernel, dim3(1), dim3(64), 0, stream,
                       ws, Wf2, bf2, Wf3, bf3, out);
}